// Round 6
// baseline (211.712 us; speedup 1.0000x reference)
//
#include <hip/hip_runtime.h>
#include <math.h>

// Problem constants (reference: B=2, S=T=400, D=512)
#define BB 2
#define SS 400
#define DD 512
#define TWO_LOG2E 2.8853900817779268f   // tanh(x) = 1 - 2/(exp2(TWO_LOG2E*x)+1)

#if __has_builtin(__builtin_amdgcn_exp2f)
#define EXP2F(x) __builtin_amdgcn_exp2f(x)
#else
#define EXP2F(x) exp2f(x)
#endif
#define RCPF(x) __builtin_amdgcn_rcpf(x)

// Workspace float layout:
//   ta   [0,       409600) : tanh(input@Wq + bq)                  [B,T,D]
//   M    [409600,  819200) : mb@Wout_top                          [B,S,D]
//   tbT4 [819200, 1228800) : tanh(mb@Wc), packed [B][D/4][S][4]
//   part [1228800,2508800) : partial scores, [eq][B][T][S] (4x320000)
// out0 gets input@Wout_bot + bout from k1 (m==3); k3 adds align@M in-place.
#define TAOFF 0
#define MOFF 409600
#define TBT4OFF 819200
#define PARTOFF 1228800
#define PARTCH 320000

__device__ __forceinline__ float tanh_fast(float x) {
    return fmaf(-2.f, RCPF(EXP2F(TWO_LOG2E * x) + 1.f), 1.f);
}

// ---------------------------------------------------------------------------
// K1: four GEMMs (800x512x512). Grid (100 rowgroups, 2 colgroups, 4 gemms)
// = 800 blocks, 256 thr; thread = 8 rows x 1 col (8 acc).
// W loads: dword coalesced. A loads: wave-uniform float4 -> compiler
// scalarizes to s_load (R5 evidence: VGPR 28 / SGPR 112).
// 2-phase pipelined K loop. W vector demand 0.5 B/FMA (~400 MB L1 total).
// ---------------------------------------------------------------------------
__global__ __launch_bounds__(256) void k1_gemm(
    const float* __restrict__ input, const float* __restrict__ mb,
    const float* __restrict__ Wq, const float* __restrict__ bq,
    const float* __restrict__ Wc, const float* __restrict__ Wout,
    const float* __restrict__ bout, float* __restrict__ ws,
    float* __restrict__ out0)
{
    const int d  = blockIdx.y * 256 + threadIdx.x;   // 0..511
    const int r0 = blockIdx.x * 8;                   // row base
    const int m  = blockIdx.z;

    const float* __restrict__ A = (m == 0 || m == 3) ? input : mb;
    const float* __restrict__ W =
        (m == 0) ? Wq : (m == 1) ? Wc : (m == 2) ? Wout : Wout + DD * DD;

    const float* __restrict__ Ab = A + (size_t)r0 * DD;
    const float* __restrict__ Wp = W + d;

    float acc[8];
    #pragma unroll
    for (int r = 0; r < 8; ++r) acc[r] = 0.f;

    float4 aA[8], aB[8];
    float  wA[4], wB[4];

    auto LOAD = [&](float4 (&aa)[8], float (&ww)[4], int ee) {
        #pragma unroll
        for (int r = 0; r < 8; ++r)
            aa[r] = *(const float4*)(Ab + (size_t)r * DD + ee);
        #pragma unroll
        for (int j = 0; j < 4; ++j)
            ww[j] = Wp[(size_t)(ee + j) * DD];
    };
    auto FMA4 = [&](const float4 (&aa)[8], const float (&ww)[4]) {
        #pragma unroll
        for (int j = 0; j < 4; ++j) {
            #pragma unroll
            for (int r = 0; r < 8; ++r) {
                const float av = (j == 0) ? aa[r].x : (j == 1) ? aa[r].y
                               : (j == 2) ? aa[r].z : aa[r].w;
                acc[r] = fmaf(av, ww[j], acc[r]);
            }
        }
    };

    LOAD(aA, wA, 0);
    for (int e = 0; e < DD; e += 8) {
        LOAD(aB, wB, e + 4);
        FMA4(aA, wA);
        if (e + 8 < DD) LOAD(aA, wA, e + 8);
        FMA4(aB, wB);
    }

    if (m == 0) {
        const float b0 = bq[d];
        #pragma unroll
        for (int r = 0; r < 8; ++r)
            ws[TAOFF + (size_t)(r0 + r) * DD + d] = tanh_fast(acc[r] + b0);
    } else if (m == 1) {
        const int b   = (r0 >= SS) ? 1 : 0;
        const int sl0 = r0 - b * SS;
        // tbT4 flat idx: ((b*128 + d/4)*400 + s)*4 + (d&3)
        float* base = ws + TBT4OFF +
            (size_t)(((b * 128 + (d >> 2)) * SS + sl0) * 4 + (d & 3));
        #pragma unroll
        for (int r = 0; r < 8; ++r)
            base[r * 4] = tanh_fast(acc[r]);
    } else if (m == 2) {
        #pragma unroll
        for (int r = 0; r < 8; ++r)
            ws[MOFF + (size_t)(r0 + r) * DD + d] = acc[r];
    } else {
        const float b0 = bout[d];
        const int b  = (r0 >= SS) ? 1 : 0;
        const int tb = r0 - b * SS;
        #pragma unroll
        for (int r = 0; r < 8; ++r)
            out0[((size_t)((tb + r) * BB + b)) * DD + d] = acc[r] + b0;
    }
}

// ---------------------------------------------------------------------------
// K2a: partial scores over an e-quarter. Grid (200 t-pairs, 2 b, 4 eq),
// 448 thr; thread = s. score_part = sum_e v[e]*(ta+tb)/(1+ta*tb).
// tb: float4-packed coalesced; ta/v: block-uniform scalar path.
// 1600 blocks -> 10.9 waves/SIMD.
// ---------------------------------------------------------------------------
__global__ __launch_bounds__(448) void k2a_score(
    const float* __restrict__ ws, const float* __restrict__ v,
    float* __restrict__ part)
{
    const int tp = blockIdx.x;            // 0..199
    const int b  = blockIdx.y;
    const int eq = blockIdx.z;            // 0..3
    const int t0 = tp * 2;
    const int t1 = t0 + 1;
    const int s  = threadIdx.x;
    const int sidx = (s < SS) ? s : 0;
    const int e0 = eq * 128;

    const float4* __restrict__ tb4 =
        (const float4*)(ws + TBT4OFF) + ((size_t)b * 128 + (e0 >> 2)) * SS + sidx;
    const float* __restrict__ ta0 = ws + TAOFF + ((size_t)(b * SS + t0)) * DD + e0;
    const float* __restrict__ ta1 = ta0 + DD;
    const float* __restrict__ vp  = v + e0;

    float acc0A = 0.f, acc0B = 0.f, acc1A = 0.f, acc1B = 0.f;
    #pragma unroll 8
    for (int e4 = 0; e4 < 32; ++e4) {
        const float4 tb = tb4[(size_t)e4 * SS];
        const int e = e4 * 4;
        {
            const float a0 = ta0[e], a1 = ta1[e], vv = vp[e];
            const float r0 = RCPF(fmaf(a0, tb.x, 1.f));
            const float r1 = RCPF(fmaf(a1, tb.x, 1.f));
            acc0A = fmaf(vv, (a0 + tb.x) * r0, acc0A);
            acc1A = fmaf(vv, (a1 + tb.x) * r1, acc1A);
        }
        {
            const float a0 = ta0[e + 1], a1 = ta1[e + 1], vv = vp[e + 1];
            const float r0 = RCPF(fmaf(a0, tb.y, 1.f));
            const float r1 = RCPF(fmaf(a1, tb.y, 1.f));
            acc0B = fmaf(vv, (a0 + tb.y) * r0, acc0B);
            acc1B = fmaf(vv, (a1 + tb.y) * r1, acc1B);
        }
        {
            const float a0 = ta0[e + 2], a1 = ta1[e + 2], vv = vp[e + 2];
            const float r0 = RCPF(fmaf(a0, tb.z, 1.f));
            const float r1 = RCPF(fmaf(a1, tb.z, 1.f));
            acc0A = fmaf(vv, (a0 + tb.z) * r0, acc0A);
            acc1A = fmaf(vv, (a1 + tb.z) * r1, acc1A);
        }
        {
            const float a0 = ta0[e + 3], a1 = ta1[e + 3], vv = vp[e + 3];
            const float r0 = RCPF(fmaf(a0, tb.w, 1.f));
            const float r1 = RCPF(fmaf(a1, tb.w, 1.f));
            acc0B = fmaf(vv, (a0 + tb.w) * r0, acc0B);
            acc1B = fmaf(vv, (a1 + tb.w) * r1, acc1B);
        }
    }

    if (s < SS) {
        float* __restrict__ pp = part + (size_t)eq * PARTCH;
        pp[((size_t)(b * SS + t0)) * SS + s] = acc0A + acc0B;
        pp[((size_t)(b * SS + t1)) * SS + s] = acc1A + acc1B;
    }
}

// ---------------------------------------------------------------------------
// K2b: combine 4 partials, mask, softmax, write align [T,B,S]. Grid 800.
// ---------------------------------------------------------------------------
__global__ __launch_bounds__(448) void k2b_softmax(
    const float* __restrict__ part, const int* __restrict__ lens,
    float* __restrict__ align_out)
{
    const int bt = blockIdx.x;            // b*SS + t
    const int b  = bt / SS;
    const int t  = bt - b * SS;
    const int tid = threadIdx.x;
    const int s   = tid;
    const int len = lens[b];

    float sc = -INFINITY;
    bool valid = false;
    if (s < SS) {
        valid = (s < len) && (s != t);
        if (valid) {
            const size_t idx = (size_t)bt * SS + s;
            sc = (part[idx] + part[PARTCH + idx])
               + (part[2 * (size_t)PARTCH + idx] + part[3 * (size_t)PARTCH + idx]);
        }
    }

    __shared__ float wred[8];
    const int wid  = tid >> 6;
    const int lane = tid & 63;

    float m = sc;
    #pragma unroll
    for (int off = 32; off > 0; off >>= 1) m = fmaxf(m, __shfl_xor(m, off));
    if (lane == 0) wred[wid] = m;
    __syncthreads();
    float mx = wred[0];
    #pragma unroll
    for (int w = 1; w < 7; ++w) mx = fmaxf(mx, wred[w]);
    __syncthreads();

    const float p = valid ? __expf(sc - mx) : 0.f;
    float sm = p;
    #pragma unroll
    for (int off = 32; off > 0; off >>= 1) sm += __shfl_xor(sm, off);
    if (lane == 0) wred[wid] = sm;
    __syncthreads();
    float tot = wred[0];
    #pragma unroll
    for (int w = 1; w < 7; ++w) tot += wred[w];
    const float inv = RCPF(tot);

    if (s < SS) align_out[((size_t)(t * BB) + b) * SS + s] = p * inv;
}

// ---------------------------------------------------------------------------
// K3: out0[t,b,d] += sum_s align[t,b,s] * M[b,s,d]. Grid (2,200), 256 thr.
// Thread = 4 t-rows x 1 d col; full s per block (no atomics); 2-phase
// prefetch. 400 blocks.
// ---------------------------------------------------------------------------
__global__ __launch_bounds__(256) void k3_out(
    const float* __restrict__ ws, const float* __restrict__ align_out,
    float* __restrict__ out0)
{
    const int d     = blockIdx.x * 256 + threadIdx.x;
    const int r0    = blockIdx.y * 4;
    const int b     = (r0 >= SS) ? 1 : 0;
    const int tbase = r0 - b * SS;

    const float* __restrict__ Mb = ws + MOFF + (size_t)b * SS * DD;

    float pv[4];
    #pragma unroll
    for (int j = 0; j < 4; ++j)
        pv[j] = out0[((size_t)((tbase + j) * BB) + b) * DD + d];

    float acc[4];
    #pragma unroll
    for (int j = 0; j < 4; ++j) acc[j] = 0.f;

    float mA[4], mB[4];
    float4 alA[4], alB[4];

    auto LOAD = [&](float (&mm)[4], float4 (&al)[4], int s) {
        #pragma unroll
        for (int i = 0; i < 4; ++i)
            mm[i] = Mb[(size_t)(s + i) * DD + d];
        #pragma unroll
        for (int j = 0; j < 4; ++j)
            al[j] = *(const float4*)(align_out +
                     ((size_t)((tbase + j) * BB) + b) * SS + s);
    };
    auto FMA4 = [&](const float (&mm)[4], const float4 (&al)[4]) {
        #pragma unroll
        for (int j = 0; j < 4; ++j) {
            acc[j] = fmaf(al[j].x, mm[0], acc[j]);
            acc[j] = fmaf(al[j].y, mm[1], acc[j]);
            acc[j] = fmaf(al[j].z, mm[2], acc[j]);
            acc[j] = fmaf(al[j].w, mm[3], acc[j]);
        }
    };

    LOAD(mA, alA, 0);
    for (int s = 0; s < SS; s += 8) {
        LOAD(mB, alB, s + 4);
        FMA4(mA, alA);
        if (s + 8 < SS) LOAD(mA, alA, s + 8);
        FMA4(mB, alB);
    }

    #pragma unroll
    for (int j = 0; j < 4; ++j)
        out0[((size_t)((tbase + j) * BB) + b) * DD + d] = acc[j] + pv[j];
}

// ---------------------------------------------------------------------------
extern "C" void kernel_launch(void* const* d_in, const int* in_sizes, int n_in,
                              void* d_out, int out_size, void* d_ws, size_t ws_size,
                              hipStream_t stream)
{
    const float* input = (const float*)d_in[0];
    const float* mb    = (const float*)d_in[1];
    const int*   lens  = (const int*)d_in[2];
    const float* Wq    = (const float*)d_in[3];
    const float* bq    = (const float*)d_in[4];
    const float* Wc    = (const float*)d_in[5];
    const float* v     = (const float*)d_in[6];
    const float* Wout  = (const float*)d_in[7];
    const float* bout  = (const float*)d_in[8];

    float* out0 = (float*)d_out;               // [T,B,D] = 409600
    float* out1 = out0 + (size_t)BB * SS * DD; // [T,B,S] = 320000
    float* ws   = (float*)d_ws;

    hipLaunchKernelGGL(k1_gemm, dim3(100, 2, 4), dim3(256), 0, stream,
                       input, mb, Wq, bq, Wc, Wout, bout, ws, out0);
    hipLaunchKernelGGL(k2a_score, dim3(200, 2, 4), dim3(448), 0, stream,
                       ws, v, ws + PARTOFF);
    hipLaunchKernelGGL(k2b_softmax, dim3(800), dim3(448), 0, stream,
                       ws + PARTOFF, lens, out1);
    hipLaunchKernelGGL(k3_out, dim3(2, 200), dim3(256), 0, stream,
                       ws, out1, out0);
}

// Round 7
// 184.308 us; speedup vs baseline: 1.1487x; 1.1487x over previous
//
#include <hip/hip_runtime.h>
#include <math.h>

// Problem constants (reference: B=2, S=T=400, D=512)
#define BB 2
#define SS 400
#define DD 512
#define TWO_LOG2E 2.8853900817779268f   // tanh(x) = 1 - 2/(exp2(TWO_LOG2E*x)+1)

#if __has_builtin(__builtin_amdgcn_exp2f)
#define EXP2F(x) __builtin_amdgcn_exp2f(x)
#else
#define EXP2F(x) exp2f(x)
#endif
#define RCPF(x) __builtin_amdgcn_rcpf(x)

// Workspace float layout:
//   ta   [0,       409600) : tanh(input@Wq + bq)                  [B,T,D]
//   M    [409600,  819200) : mb@Wout_top                          [B,S,D]
//   tbT4 [819200, 1228800) : tanh(mb@Wc), packed [B][D/4][S][4]
//   part [1228800,2508800) : partial scores, [eq][B][T][S] (4x320000)
// out0 gets input@Wout_bot + bout from k1 (m==3); k3 adds align@M in-place.
#define TAOFF 0
#define MOFF 409600
#define TBT4OFF 819200
#define PARTOFF 1228800
#define PARTCH 320000

__device__ __forceinline__ float tanh_fast(float x) {
    return fmaf(-2.f, RCPF(EXP2F(TWO_LOG2E * x) + 1.f), 1.f);
}

// ---------------------------------------------------------------------------
// K1: four GEMMs (800x512x512) as classic LDS double-buffered GEMM.
// BM=64, BN=64, BK=32, 256 thr, thread tile 4x4, grid (13,8,4)=416 blocks.
// As stored k-major [k][row] (+1 pad) so compute reads are ds_read_b128 for
// both A and B. Latency hidden by ILP (512 FMA/tile between barriers), not
// wave count. Rows >= 800 clamped on load, guarded on store.
// Fused epilogues: m0 ta=tanh(acc+bq); m1 tbT4 (transposed pack — one
// contiguous float4 per (s, d-group)); m2 M; m3 out0=acc+bout [T,B,D].
// ---------------------------------------------------------------------------
__global__ __launch_bounds__(256) void k1_gemm(
    const float* __restrict__ input, const float* __restrict__ mb,
    const float* __restrict__ Wq, const float* __restrict__ bq,
    const float* __restrict__ Wc, const float* __restrict__ Wout,
    const float* __restrict__ bout, float* __restrict__ ws,
    float* __restrict__ out0)
{
    const int tx = threadIdx.x & 15;        // col group 0..15
    const int ty = threadIdx.x >> 4;        // row group 0..15
    const int c0 = blockIdx.y * 64;
    const int r0 = blockIdx.x * 64;
    const int m  = blockIdx.z;

    const float* __restrict__ A = (m == 0 || m == 3) ? input : mb;
    const float* __restrict__ W =
        (m == 0) ? Wq : (m == 1) ? Wc : (m == 2) ? Wout : Wout + DD * DD;

    __shared__ float As[2][32][65];   // [buf][k][row], +1 pad
    __shared__ float Bs[2][32][64];   // [buf][k][col]

    // loader indices
    const int lar = threadIdx.x >> 3;         // A: row within pass 0..31
    const int lak = (threadIdx.x & 7) * 4;    // A: k offset 0..28
    const int lbk = threadIdx.x >> 4;         // B: k-row within pass 0..15
    const int lbc = (threadIdx.x & 15) * 4;   // B: col 0..60

    float4 aR[2], bR[2];
    auto GLOAD = [&](int kk) {
        #pragma unroll
        for (int p = 0; p < 2; ++p) {
            int gr = r0 + lar + p * 32;
            if (gr > 799) gr = 799;           // clamp (result discarded)
            aR[p] = *(const float4*)(A + (size_t)gr * DD + kk + lak);
            bR[p] = *(const float4*)(W + (size_t)(kk + lbk + p * 16) * DD + c0 + lbc);
        }
    };
    auto SSTORE = [&](int buf) {
        #pragma unroll
        for (int p = 0; p < 2; ++p) {
            #pragma unroll
            for (int j = 0; j < 4; ++j)
                As[buf][lak + j][lar + p * 32] = (&aR[p].x)[j];
            *(float4*)&Bs[buf][lbk + p * 16][lbc] = bR[p];
        }
    };

    float4 acc[4];
    #pragma unroll
    for (int i = 0; i < 4; ++i) acc[i] = make_float4(0.f, 0.f, 0.f, 0.f);

    GLOAD(0);
    SSTORE(0);
    __syncthreads();

    for (int t = 0; t < 16; ++t) {
        const int buf = t & 1;
        if (t < 15) GLOAD((t + 1) * 32);
        #pragma unroll 8
        for (int k = 0; k < 32; ++k) {
            const float4 a = *(const float4*)&As[buf][k][ty * 4];
            const float4 b = *(const float4*)&Bs[buf][k][tx * 4];
            #pragma unroll
            for (int i = 0; i < 4; ++i) {
                const float av = (&a.x)[i];
                acc[i].x = fmaf(av, b.x, acc[i].x);
                acc[i].y = fmaf(av, b.y, acc[i].y);
                acc[i].z = fmaf(av, b.z, acc[i].z);
                acc[i].w = fmaf(av, b.w, acc[i].w);
            }
        }
        if (t < 15) {
            __syncthreads();      // all waves done reading buf^1 (tile t-1)
            SSTORE(buf ^ 1);
            __syncthreads();      // stores visible before compute(t+1)
        }
    }

    const int col = c0 + tx * 4;
    if (m == 0) {
        const float4 bqv = *(const float4*)(bq + col);
        #pragma unroll
        for (int i = 0; i < 4; ++i) {
            const int gr = r0 + ty * 4 + i;
            if (gr >= 800) break;
            float4 o;
            o.x = tanh_fast(acc[i].x + bqv.x);
            o.y = tanh_fast(acc[i].y + bqv.y);
            o.z = tanh_fast(acc[i].z + bqv.z);
            o.w = tanh_fast(acc[i].w + bqv.w);
            *(float4*)(ws + TAOFF + (size_t)gr * DD + col) = o;
        }
    } else if (m == 1) {
        #pragma unroll
        for (int i = 0; i < 4; ++i) {
            const int gr = r0 + ty * 4 + i;
            if (gr >= 800) break;
            const int bi = (gr >= SS) ? 1 : 0;
            const int sl = gr - bi * SS;
            float4 o;
            o.x = tanh_fast(acc[i].x);
            o.y = tanh_fast(acc[i].y);
            o.z = tanh_fast(acc[i].z);
            o.w = tanh_fast(acc[i].w);
            ((float4*)(ws + TBT4OFF))[((size_t)bi * 128 + (col >> 2)) * SS + sl] = o;
        }
    } else if (m == 2) {
        #pragma unroll
        for (int i = 0; i < 4; ++i) {
            const int gr = r0 + ty * 4 + i;
            if (gr >= 800) break;
            *(float4*)(ws + MOFF + (size_t)gr * DD + col) = acc[i];
        }
    } else {
        const float4 bo = *(const float4*)(bout + col);
        #pragma unroll
        for (int i = 0; i < 4; ++i) {
            const int gr = r0 + ty * 4 + i;
            if (gr >= 800) break;
            const int bi = (gr >= SS) ? 1 : 0;
            const int tb = gr - bi * SS;
            float4 o;
            o.x = acc[i].x + bo.x;
            o.y = acc[i].y + bo.y;
            o.z = acc[i].z + bo.z;
            o.w = acc[i].w + bo.w;
            *(float4*)(out0 + ((size_t)(tb * BB + bi)) * DD + col) = o;
        }
    }
}

// ---------------------------------------------------------------------------
// K2a: partial scores over an e-quarter. Grid (200 t-pairs, 2 b, 4 eq),
// 448 thr; thread = s. score_part = sum_e v[e]*(ta+tb)/(1+ta*tb).
// tb: float4-packed coalesced; ta/v: block-uniform scalar path.
// ---------------------------------------------------------------------------
__global__ __launch_bounds__(448) void k2a_score(
    const float* __restrict__ ws, const float* __restrict__ v,
    float* __restrict__ part)
{
    const int tp = blockIdx.x;            // 0..199
    const int b  = blockIdx.y;
    const int eq = blockIdx.z;            // 0..3
    const int t0 = tp * 2;
    const int t1 = t0 + 1;
    const int s  = threadIdx.x;
    const int sidx = (s < SS) ? s : 0;
    const int e0 = eq * 128;

    const float4* __restrict__ tb4 =
        (const float4*)(ws + TBT4OFF) + ((size_t)b * 128 + (e0 >> 2)) * SS + sidx;
    const float* __restrict__ ta0 = ws + TAOFF + ((size_t)(b * SS + t0)) * DD + e0;
    const float* __restrict__ ta1 = ta0 + DD;
    const float* __restrict__ vp  = v + e0;

    float acc0A = 0.f, acc0B = 0.f, acc1A = 0.f, acc1B = 0.f;
    #pragma unroll 8
    for (int e4 = 0; e4 < 32; ++e4) {
        const float4 tb = tb4[(size_t)e4 * SS];
        const int e = e4 * 4;
        {
            const float a0 = ta0[e], a1 = ta1[e], vv = vp[e];
            const float r0 = RCPF(fmaf(a0, tb.x, 1.f));
            const float r1 = RCPF(fmaf(a1, tb.x, 1.f));
            acc0A = fmaf(vv, (a0 + tb.x) * r0, acc0A);
            acc1A = fmaf(vv, (a1 + tb.x) * r1, acc1A);
        }
        {
            const float a0 = ta0[e + 1], a1 = ta1[e + 1], vv = vp[e + 1];
            const float r0 = RCPF(fmaf(a0, tb.y, 1.f));
            const float r1 = RCPF(fmaf(a1, tb.y, 1.f));
            acc0B = fmaf(vv, (a0 + tb.y) * r0, acc0B);
            acc1B = fmaf(vv, (a1 + tb.y) * r1, acc1B);
        }
        {
            const float a0 = ta0[e + 2], a1 = ta1[e + 2], vv = vp[e + 2];
            const float r0 = RCPF(fmaf(a0, tb.z, 1.f));
            const float r1 = RCPF(fmaf(a1, tb.z, 1.f));
            acc0A = fmaf(vv, (a0 + tb.z) * r0, acc0A);
            acc1A = fmaf(vv, (a1 + tb.z) * r1, acc1A);
        }
        {
            const float a0 = ta0[e + 3], a1 = ta1[e + 3], vv = vp[e + 3];
            const float r0 = RCPF(fmaf(a0, tb.w, 1.f));
            const float r1 = RCPF(fmaf(a1, tb.w, 1.f));
            acc0B = fmaf(vv, (a0 + tb.w) * r0, acc0B);
            acc1B = fmaf(vv, (a1 + tb.w) * r1, acc1B);
        }
    }

    if (s < SS) {
        float* __restrict__ pp = part + (size_t)eq * PARTCH;
        pp[((size_t)(b * SS + t0)) * SS + s] = acc0A + acc0B;
        pp[((size_t)(b * SS + t1)) * SS + s] = acc1A + acc1B;
    }
}

// ---------------------------------------------------------------------------
// K2b: combine 4 partials, mask, softmax, write align [T,B,S]. Grid 800.
// ---------------------------------------------------------------------------
__global__ __launch_bounds__(448) void k2b_softmax(
    const float* __restrict__ part, const int* __restrict__ lens,
    float* __restrict__ align_out)
{
    const int bt = blockIdx.x;            // b*SS + t
    const int b  = bt / SS;
    const int t  = bt - b * SS;
    const int tid = threadIdx.x;
    const int s   = tid;
    const int len = lens[b];

    float sc = -INFINITY;
    bool valid = false;
    if (s < SS) {
        valid = (s < len) && (s != t);
        if (valid) {
            const size_t idx = (size_t)bt * SS + s;
            sc = (part[idx] + part[PARTCH + idx])
               + (part[2 * (size_t)PARTCH + idx] + part[3 * (size_t)PARTCH + idx]);
        }
    }

    __shared__ float wred[8];
    const int wid  = tid >> 6;
    const int lane = tid & 63;

    float m = sc;
    #pragma unroll
    for (int off = 32; off > 0; off >>= 1) m = fmaxf(m, __shfl_xor(m, off));
    if (lane == 0) wred[wid] = m;
    __syncthreads();
    float mx = wred[0];
    #pragma unroll
    for (int w = 1; w < 7; ++w) mx = fmaxf(mx, wred[w]);
    __syncthreads();

    const float p = valid ? __expf(sc - mx) : 0.f;
    float sm = p;
    #pragma unroll
    for (int off = 32; off > 0; off >>= 1) sm += __shfl_xor(sm, off);
    if (lane == 0) wred[wid] = sm;
    __syncthreads();
    float tot = wred[0];
    #pragma unroll
    for (int w = 1; w < 7; ++w) tot += wred[w];
    const float inv = RCPF(tot);

    if (s < SS) align_out[((size_t)(t * BB) + b) * SS + s] = p * inv;
}

// ---------------------------------------------------------------------------
// K3: out0[t,b,d] += sum_s align[t,b,s] * M[b,s,d]. Grid (2,200), 256 thr.
// Thread = 4 t-rows x 1 d col; full s per block (no atomics); 2-phase
// prefetch.
// ---------------------------------------------------------------------------
__global__ __launch_bounds__(256) void k3_out(
    const float* __restrict__ ws, const float* __restrict__ align_out,
    float* __restrict__ out0)
{
    const int d     = blockIdx.x * 256 + threadIdx.x;
    const int r0    = blockIdx.y * 4;
    const int b     = (r0 >= SS) ? 1 : 0;
    const int tbase = r0 - b * SS;

    const float* __restrict__ Mb = ws + MOFF + (size_t)b * SS * DD;

    float pv[4];
    #pragma unroll
    for (int j = 0; j < 4; ++j)
        pv[j] = out0[((size_t)((tbase + j) * BB) + b) * DD + d];

    float acc[4];
    #pragma unroll
    for (int j = 0; j < 4; ++j) acc[j] = 0.f;

    float mA[4], mB[4];
    float4 alA[4], alB[4];

    auto LOAD = [&](float (&mm)[4], float4 (&al)[4], int s) {
        #pragma unroll
        for (int i = 0; i < 4; ++i)
            mm[i] = Mb[(size_t)(s + i) * DD + d];
        #pragma unroll
        for (int j = 0; j < 4; ++j)
            al[j] = *(const float4*)(align_out +
                     ((size_t)((tbase + j) * BB) + b) * SS + s);
    };
    auto FMA4 = [&](const float (&mm)[4], const float4 (&al)[4]) {
        #pragma unroll
        for (int j = 0; j < 4; ++j) {
            acc[j] = fmaf(al[j].x, mm[0], acc[j]);
            acc[j] = fmaf(al[j].y, mm[1], acc[j]);
            acc[j] = fmaf(al[j].z, mm[2], acc[j]);
            acc[j] = fmaf(al[j].w, mm[3], acc[j]);
        }
    };

    LOAD(mA, alA, 0);
    for (int s = 0; s < SS; s += 8) {
        LOAD(mB, alB, s + 4);
        FMA4(mA, alA);
        if (s + 8 < SS) LOAD(mA, alA, s + 8);
        FMA4(mB, alB);
    }

    #pragma unroll
    for (int j = 0; j < 4; ++j)
        out0[((size_t)((tbase + j) * BB) + b) * DD + d] = acc[j] + pv[j];
}

// ---------------------------------------------------------------------------
extern "C" void kernel_launch(void* const* d_in, const int* in_sizes, int n_in,
                              void* d_out, int out_size, void* d_ws, size_t ws_size,
                              hipStream_t stream)
{
    const float* input = (const float*)d_in[0];
    const float* mb    = (const float*)d_in[1];
    const int*   lens  = (const int*)d_in[2];
    const float* Wq    = (const float*)d_in[3];
    const float* bq    = (const float*)d_in[4];
    const float* Wc    = (const float*)d_in[5];
    const float* v     = (const float*)d_in[6];
    const float* Wout  = (const float*)d_in[7];
    const float* bout  = (const float*)d_in[8];

    float* out0 = (float*)d_out;               // [T,B,D] = 409600
    float* out1 = out0 + (size_t)BB * SS * DD; // [T,B,S] = 320000
    float* ws   = (float*)d_ws;

    hipLaunchKernelGGL(k1_gemm, dim3(13, 8, 4), dim3(256), 0, stream,
                       input, mb, Wq, bq, Wc, Wout, bout, ws, out0);
    hipLaunchKernelGGL(k2a_score, dim3(200, 2, 4), dim3(448), 0, stream,
                       ws, v, ws + PARTOFF);
    hipLaunchKernelGGL(k2b_softmax, dim3(800), dim3(448), 0, stream,
                       ws + PARTOFF, lens, out1);
    hipLaunchKernelGGL(k3_out, dim3(2, 200), dim3(256), 0, stream,
                       ws, out1, out0);
}